// Round 2
// baseline (140.263 us; speedup 1.0000x reference)
//
#include <hip/hip_runtime.h>
#include <hip/hip_bf16.h>

typedef __bf16 bf16x8 __attribute__((ext_vector_type(8)));
typedef float  f32x4  __attribute__((ext_vector_type(4)));

#define LRELU_ALPHA 0.2f

__device__ __forceinline__ float lrelu(float x) { return x > 0.f ? x : LRELU_ALPHA * x; }

// ---------------------------------------------------------------------------
// Kernel 1: h = inp @ W  (one row per block, 128 threads), plus f1 = h·a1,
// f2 = h·a2. h kept fp32 (residual path needs it).
// ---------------------------------------------------------------------------
__global__ __launch_bounds__(128) void gat_prep(
    const float* __restrict__ inp, const float* __restrict__ W,
    const float* __restrict__ a,
    float* __restrict__ h, float* __restrict__ f1, float* __restrict__ f2)
{
    const int r = blockIdx.x;            // global row 0..16383
    const int d = threadIdx.x;           // 0..127
    __shared__ float sIn[128];
    __shared__ float sRed[4];
    sIn[d] = inp[(size_t)r * 128 + d];
    __syncthreads();
    float acc = 0.f;
    #pragma unroll 8
    for (int k = 0; k < 128; ++k) acc += sIn[k] * W[k * 128 + d];
    h[(size_t)r * 128 + d] = acc;
    float t1 = acc * a[d];
    float t2 = acc * a[128 + d];
    #pragma unroll
    for (int m = 1; m < 64; m <<= 1) {
        t1 += __shfl_xor(t1, m);
        t2 += __shfl_xor(t2, m);
    }
    const int wave = d >> 6;
    if ((d & 63) == 0) { sRed[wave] = t1; sRed[2 + wave] = t2; }
    __syncthreads();
    if (d == 0) {
        f1[r] = sRed[0] + sRed[1];
        f2[r] = sRed[2] + sRed[3];
    }
}

// ---------------------------------------------------------------------------
// Kernel 2: per-batch max of f1 (exact softmax stabilizer bound)
// ---------------------------------------------------------------------------
__global__ __launch_bounds__(256) void gat_f1max(
    const float* __restrict__ f1, float* __restrict__ f1max)
{
    const int b = blockIdx.x;
    const int t = threadIdx.x;
    float m = -1e30f;
    for (int j = t; j < 2048; j += 256) m = fmaxf(m, f1[b * 2048 + j]);
    #pragma unroll
    for (int k = 1; k < 64; k <<= 1) m = fmaxf(m, __shfl_xor(m, k));
    __shared__ float sm[4];
    if ((t & 63) == 0) sm[t >> 6] = m;
    __syncthreads();
    if (t == 0) f1max[b] = fmaxf(fmaxf(sm[0], sm[1]), fmaxf(sm[2], sm[3]));
}

// ---------------------------------------------------------------------------
// Kernel 3: transpose h (fp32, [b][n][128]) -> hT (bf16, [b][128][2048])
// so the MFMA B-operand is a contiguous k-minor 16B load. LDS-tiled 64x64.
// ---------------------------------------------------------------------------
__global__ __launch_bounds__(256) void gat_transpose(
    const float* __restrict__ h, __bf16* __restrict__ hT)
{
    __shared__ __bf16 tile[64][72];      // padded
    const int tid = threadIdx.x;
    const int bidx = blockIdx.x;         // 8 * 32 * 2 = 512 blocks
    const int b  = bidx >> 6;
    const int tI = bidx & 63;
    const int n0 = (tI >> 1) << 6;
    const int d0 = (tI & 1) << 6;
    #pragma unroll
    for (int pass = 0; pass < 2; ++pass) {
        int row = (tid >> 3) + (pass << 5);     // n within tile
        int c   = (tid & 7) << 3;               // d within tile
        const float* src = h + (size_t)(b * 2048 + n0 + row) * 128 + d0 + c;
        float4 v0 = *(const float4*)src;
        float4 v1 = *(const float4*)(src + 4);
        __bf16* tp = &tile[row][c];
        tp[0]=(__bf16)v0.x; tp[1]=(__bf16)v0.y; tp[2]=(__bf16)v0.z; tp[3]=(__bf16)v0.w;
        tp[4]=(__bf16)v1.x; tp[5]=(__bf16)v1.y; tp[6]=(__bf16)v1.z; tp[7]=(__bf16)v1.w;
    }
    __syncthreads();
    #pragma unroll
    for (int pass = 0; pass < 2; ++pass) {
        int dd = (tid >> 3) + (pass << 5);      // d within tile
        int nn = (tid & 7) << 3;                // n within tile
        union { __bf16 e[8]; bf16x8 v; } u;
        #pragma unroll
        for (int x = 0; x < 8; ++x) u.e[x] = tile[nn + x][dd];
        *(bf16x8*)(hT + ((size_t)(b * 128 + d0 + dd) << 11) + n0 + nn) = u.v;
    }
}

// ---------------------------------------------------------------------------
// Kernel 4 v2: barrier-free fused attention.
// Block: 256 threads (4 waves) owns 32 i-rows. Wave w: i-group (w&1)*16,
// d-half (w>>1)*64. Each lane computes the 8 P values of its own MFMA
// A-fragment (i = lane&15, j = kb..kb+7) -> no LDS P, no barriers in loop.
// j-tile = 64 (two k-steps of 32), 32 iterations, 1-deep prefetch.
// ---------------------------------------------------------------------------

// compute one p, feed denominator, store into A-frag union slot
#define P1(U, IDX, AJC, FC) do {                                    \
    float _x = f2v + (FC);                                          \
    float _t = fmaxf(_x, LRELU_ALPHA * _x) - M;                     \
    float _p = ((AJC) > 0) ? __expf(_t) : 0.f;                      \
    __bf16 _pb = (__bf16)_p;                                        \
    ps += (float)_pb;                                               \
    (U).e[IDX] = _pb;                                               \
} while (0)

#define PREFETCH(T, A0,A1,A2,A3, B0,B1,B2,B3,B4,B5,B6,B7) do {      \
    const int _j0 = (T) << 6;                                       \
    A0 = *(const int4*)(ajp + _j0);                                 \
    A1 = *(const int4*)(ajp + _j0 + 4);                             \
    A2 = *(const int4*)(ajp + _j0 + 32);                            \
    A3 = *(const int4*)(ajp + _j0 + 36);                            \
    B0 = *(const bf16x8*)(hTb + _j0);                               \
    B1 = *(const bf16x8*)(hTb + _j0 + 32);                          \
    B2 = *(const bf16x8*)(hTb + (1 << 15) + _j0);                   \
    B3 = *(const bf16x8*)(hTb + (1 << 15) + _j0 + 32);              \
    B4 = *(const bf16x8*)(hTb + (2 << 15) + _j0);                   \
    B5 = *(const bf16x8*)(hTb + (2 << 15) + _j0 + 32);              \
    B6 = *(const bf16x8*)(hTb + (3 << 15) + _j0);                   \
    B7 = *(const bf16x8*)(hTb + (3 << 15) + _j0 + 32);              \
} while (0)

#define BODY(T, A0,A1,A2,A3, B0,B1,B2,B3,B4,B5,B6,B7) do {          \
    const int _j0 = (T) << 6;                                       \
    float4 _fa = *(const float4*)&f1s[_j0 + kb];                    \
    float4 _fb = *(const float4*)&f1s[_j0 + kb + 4];                \
    float4 _fc = *(const float4*)&f1s[_j0 + 32 + kb];               \
    float4 _fd = *(const float4*)&f1s[_j0 + 32 + kb + 4];           \
    union { __bf16 e[8]; bf16x8 v; } _u0, _u1;                      \
    P1(_u0,0,A0.x,_fa.x); P1(_u0,1,A0.y,_fa.y);                     \
    P1(_u0,2,A0.z,_fa.z); P1(_u0,3,A0.w,_fa.w);                     \
    P1(_u0,4,A1.x,_fb.x); P1(_u0,5,A1.y,_fb.y);                     \
    P1(_u0,6,A1.z,_fb.z); P1(_u0,7,A1.w,_fb.w);                     \
    P1(_u1,0,A2.x,_fc.x); P1(_u1,1,A2.y,_fc.y);                     \
    P1(_u1,2,A2.z,_fc.z); P1(_u1,3,A2.w,_fc.w);                     \
    P1(_u1,4,A3.x,_fd.x); P1(_u1,5,A3.y,_fd.y);                     \
    P1(_u1,6,A3.z,_fd.z); P1(_u1,7,A3.w,_fd.w);                     \
    acc0 = __builtin_amdgcn_mfma_f32_16x16x32_bf16(_u0.v, B0, acc0, 0,0,0); \
    acc0 = __builtin_amdgcn_mfma_f32_16x16x32_bf16(_u1.v, B1, acc0, 0,0,0); \
    acc1 = __builtin_amdgcn_mfma_f32_16x16x32_bf16(_u0.v, B2, acc1, 0,0,0); \
    acc1 = __builtin_amdgcn_mfma_f32_16x16x32_bf16(_u1.v, B3, acc1, 0,0,0); \
    acc2 = __builtin_amdgcn_mfma_f32_16x16x32_bf16(_u0.v, B4, acc2, 0,0,0); \
    acc2 = __builtin_amdgcn_mfma_f32_16x16x32_bf16(_u1.v, B5, acc2, 0,0,0); \
    acc3 = __builtin_amdgcn_mfma_f32_16x16x32_bf16(_u0.v, B6, acc3, 0,0,0); \
    acc3 = __builtin_amdgcn_mfma_f32_16x16x32_bf16(_u1.v, B7, acc3, 0,0,0); \
} while (0)

__global__ __launch_bounds__(256, 2) void gat_attn2(
    const int* __restrict__ adj, const float* __restrict__ h,
    const __bf16* __restrict__ hT, const float* __restrict__ f1g,
    const float* __restrict__ f2g, const float* __restrict__ f1maxg,
    float* __restrict__ out)
{
    const int bid = blockIdx.x;          // 8 * 64 = 512 blocks
    const int b  = bid >> 6;
    const int i0 = (bid & 63) << 5;      // 32 i-rows per block
    const int tid  = threadIdx.x;
    const int w    = tid >> 6;           // wave 0..3
    const int lane = tid & 63;
    const int il   = lane & 15;
    const int kg   = lane >> 4;          // k-group 0..3
    const int kb   = kg << 3;            // 0,8,16,24
    const int ig   = w & 1;              // i-group within block
    const int dh   = w >> 1;             // d-half
    const int ibase = i0 + (ig << 4);
    const int dbase = dh << 6;

    __shared__ float f1s[2048];
    for (int idx = tid; idx < 2048; idx += 256)
        f1s[idx] = f1g[b * 2048 + idx];

    const float fm  = f1maxg[b];
    const float f2v = f2g[b * 2048 + ibase + il];
    const float M   = lrelu(f2v + fm);   // exact stabilizer: p = exp(e-M) <= 1

    const int*    ajp = adj + ((size_t)(b * 2048 + ibase + il) << 11) + kb;
    const __bf16* hTb = hT  + ((size_t)(b * 128  + dbase + il) << 11) + kb;

    f32x4 acc0 = {0.f,0.f,0.f,0.f}, acc1 = {0.f,0.f,0.f,0.f};
    f32x4 acc2 = {0.f,0.f,0.f,0.f}, acc3 = {0.f,0.f,0.f,0.f};
    float ps = 0.f;

    int4 pa0, pa1, pa2, pa3;   bf16x8 pb0, pb1, pb2, pb3, pb4, pb5, pb6, pb7;
    int4 qa0, qa1, qa2, qa3;   bf16x8 qb0, qb1, qb2, qb3, qb4, qb5, qb6, qb7;

    PREFETCH(0, pa0,pa1,pa2,pa3, pb0,pb1,pb2,pb3,pb4,pb5,pb6,pb7);
    __syncthreads();                     // f1s ready (only barrier)

    for (int t = 0; t < 32; t += 2) {
        PREFETCH(t + 1, qa0,qa1,qa2,qa3, qb0,qb1,qb2,qb3,qb4,qb5,qb6,qb7);
        BODY(t, pa0,pa1,pa2,pa3, pb0,pb1,pb2,pb3,pb4,pb5,pb6,pb7);
        PREFETCH((t + 2) & 31, pa0,pa1,pa2,pa3, pb0,pb1,pb2,pb3,pb4,pb5,pb6,pb7);
        BODY(t + 1, qa0,qa1,qa2,qa3, qb0,qb1,qb2,qb3,qb4,qb5,qb6,qb7);
    }

    // denominator: ps currently = partial sum over this lane's j-subset.
    // xor over kg bits (lane bits 4,5) -> full sum for row il, on every lane.
    ps += __shfl_xor(ps, 16);
    ps += __shfl_xor(ps, 32);

    // epilogue: C layout row = kg*4 + r, col = il. Denominator for row R
    // lives on lane R (R<16). Normalize, elu, residual.
    #pragma unroll
    for (int r = 0; r < 4; ++r) {
        const int   row = (kg << 2) + r;
        const float den = __shfl(ps, row);
        const size_t gbase = ((size_t)(b * 2048 + ibase + row) << 7) + dbase + il;
        float v, e;
        v = acc0[r] / den; e = (v > 0.f) ? v : (__expf(v) - 1.f); out[gbase]      = e + h[gbase];
        v = acc1[r] / den; e = (v > 0.f) ? v : (__expf(v) - 1.f); out[gbase + 16] = e + h[gbase + 16];
        v = acc2[r] / den; e = (v > 0.f) ? v : (__expf(v) - 1.f); out[gbase + 32] = e + h[gbase + 32];
        v = acc3[r] / den; e = (v > 0.f) ? v : (__expf(v) - 1.f); out[gbase + 48] = e + h[gbase + 48];
    }
}

// ---------------------------------------------------------------------------
extern "C" void kernel_launch(void* const* d_in, const int* in_sizes, int n_in,
                              void* d_out, int out_size, void* d_ws, size_t ws_size,
                              hipStream_t stream)
{
    const float* inp = (const float*)d_in[0];
    const int*   adj = (const int*)d_in[1];
    const float* W   = (const float*)d_in[2];
    const float* a   = (const float*)d_in[3];
    float* out = (float*)d_out;

    // workspace layout (needs ~12.7 MB)
    char* ws = (char*)d_ws;
    float*  h     = (float*)ws;                          // 8 MB
    __bf16* hT    = (__bf16*)(ws + 8388608);             // 4 MB
    float*  f1    = (float*)(ws + 8388608 + 4194304);    // 64 KB
    float*  f2    = (float*)(ws + 8388608 + 4194304 + 65536);
    float*  f1max = (float*)(ws + 8388608 + 4194304 + 131072);

    gat_prep<<<16384, 128, 0, stream>>>(inp, W, a, h, f1, f2);
    gat_f1max<<<8, 256, 0, stream>>>(f1, f1max);
    gat_transpose<<<512, 256, 0, stream>>>(h, hT);
    gat_attn2<<<512, 256, 0, stream>>>(adj, h, hT, f1, f2, f1max, out);
}